// Round 11
// baseline (148.521 us; speedup 1.0000x reference)
//
#include <hip/hip_runtime.h>
#include <hip/hip_fp16.h>
#include <math.h>

#define NS 64
#define NV 16
#define NHS 32
#define NHV 16
#define NPGRID 512       // persistent blocks per side in node_pack

// den_scan geometry: grid = RANGES*SPLITS blocks of 512 threads.
// s in LOW bits: blocks sharing edge-slice s are stride-32 apart == same XCD
// under round-robin -> slice cached in that XCD's L2.
#define RANGES 8         // node ranges; rn = 6250 -> 25KB LDS
#define SPLITS 32        // edge-list splits
#define DP_STRIDE 50176  // padded per-split den stride (>= N, mult of 256)

__device__ __forceinline__ float silu_f(float x){ return x * (1.0f / (1.0f + __expf(-x))); }

__device__ __forceinline__ float packh2(float a, float b){
    __half2 h = __floats2half2_rn(a, b);
    return __uint_as_float(*(unsigned*)&h);
}
__device__ __forceinline__ float2 unpackh2(float w){
    __half2 h = *(__half2*)&w;
    return __half22float2(h);
}

// Per-node precompute: pack[n] = 32B = {A fp32, ff[9]+pos[3] as fp16}
// Register-weight design: lane = h (32 scalar rows), half-wave = one node.
// Weights live in VGPRs (loaded once); node data via uniform-address loads
// (HW broadcast). NO LDS, no __syncthreads.
__global__ __launch_bounds__(256) void node_pack_kernel(
    const float* __restrict__ from_s, const float* __restrict__ from_v,
    const float* __restrict__ from_fr, const float* __restrict__ from_p,
    const float* __restrict__ to_s, const float* __restrict__ to_v,
    const float* __restrict__ to_fr, const float* __restrict__ to_p,
    const float* __restrict__ Wfs, const float* __restrict__ Wts,
    const float* __restrict__ Wfv, const float* __restrict__ Wtv,
    const float* __restrict__ Wattn,
    float* __restrict__ packA, float* __restrict__ packB,
    int N)
{
    const int side = blockIdx.y;
    const float* node_s = side ? to_s  : from_s;
    const float* node_v = side ? to_v  : from_v;
    const float* frame  = side ? to_fr : from_fr;
    const float* pos    = side ? to_p  : from_p;
    const float* Ws     = side ? Wts   : Wfs;
    const float* Wv     = side ? Wtv   : Wfv;
    const int    s_off  = side ? 32 : 0;
    const int    v_off  = side ? 115 : 64;
    float*       pack   = side ? packB : packA;

    const int lane = threadIdx.x & 63;
    const int wid  = threadIdx.x >> 6;     // wave 0..3
    const int h    = lane & 31;            // scalar row index
    const int p    = lane >> 5;            // node slot within wave (0/1)
    const int hm   = h & 15;

    // ---- weights -> registers (once) ----
    float4 wsrow[16];
    {
        const float4* wsp = (const float4*)(Ws + h * NS);
        #pragma unroll
        for (int k4 = 0; k4 < 16; k4++) wsrow[k4] = wsp[k4];
    }
    float wvrow[16];
    {
        const float* wvp = Wv + hm * NV;
        #pragma unroll
        for (int k = 0; k < 16; k++) wvrow[k] = wvp[k];
    }
    const float waS = Wattn[s_off + h];
    float waV0 = Wattn[v_off + hm * 3 + 0];
    float waV1 = Wattn[v_off + hm * 3 + 1];
    float waV2 = Wattn[v_off + hm * 3 + 2];
    if (h >= 16){ waV0 = 0.f; waV1 = 0.f; waV2 = 0.f; }   // vector part only h<16

    const int slot   = (blockIdx.x * 4 + wid) * 2 + p;    // node id start
    const int stride = NPGRID * 8;                        // nodes per grid pass

    for (int n = slot; n < N; n += stride){
        // scalar GEMV row h: d = s[n] . Ws[h]   (uniform loads, broadcast)
        const float4* sp = (const float4*)(node_s + (size_t)n * NS);
        float d = 0.f;
        #pragma unroll
        for (int k4 = 0; k4 < 16; k4++){
            float4 sv = sp[k4];
            d += sv.x * wsrow[k4].x + sv.y * wsrow[k4].y
               + sv.z * wsrow[k4].z + sv.w * wsrow[k4].w;
        }
        float acc = silu_f(d) * waS;

        // vector GEMV row hm: a_c = sum_vv v[vv][c] * Wv[hm][vv]
        const float4* vp = (const float4*)(node_v + (size_t)n * (NV * 3));
        float a0 = 0.f, a1 = 0.f, a2 = 0.f;
        #pragma unroll
        for (int g4 = 0; g4 < 4; g4++){            // 4 vv per group, 3 float4
            float4 x = vp[g4 * 3 + 0];
            float4 y = vp[g4 * 3 + 1];
            float4 z = vp[g4 * 3 + 2];
            float w0 = wvrow[4 * g4 + 0], w1 = wvrow[4 * g4 + 1];
            float w2 = wvrow[4 * g4 + 2], w3 = wvrow[4 * g4 + 3];
            a0 += x.x * w0 + x.w * w1 + y.z * w2 + z.y * w3;
            a1 += x.y * w0 + y.x * w1 + y.w * w2 + z.z * w3;
            a2 += x.z * w0 + y.y * w1 + z.x * w2 + z.w * w3;
        }

        // frame + pos (uniform scalar loads; 4B aligned only)
        const float* fb = frame + (size_t)n * 9;
        float ff0 = fb[0], ff1 = fb[1], ff2 = fb[2];
        float ff3 = fb[3], ff4 = fb[4], ff5 = fb[5];
        float ff6 = fb[6], ff7 = fb[7], ff8 = fb[8];
        const float* pb = pos + (size_t)n * 3;
        float ps0 = pb[0], ps1 = pb[1], ps2 = pb[2];

        float t0 = a0 * ff0 + a1 * ff3 + a2 * ff6;
        float t1 = a0 * ff1 + a1 * ff4 + a2 * ff7;
        float t2 = a0 * ff2 + a1 * ff5 + a2 * ff8;
        acc += silu_f(t0) * waV0 + silu_f(t1) * waV1 + silu_f(t2) * waV2;

        // reduce over the 32 lanes of this half (masks <32 stay within half)
        acc += __shfl_xor(acc, 16);
        acc += __shfl_xor(acc, 8);
        acc += __shfl_xor(acc, 4);
        acc += __shfl_xor(acc, 2);
        acc += __shfl_xor(acc, 1);

        if (h < 2){
            float4 o;
            if (h == 0){
                o = make_float4(acc,
                                packh2(ff0, ff1),
                                packh2(ff2, ff3),
                                packh2(ff4, ff5));
            } else {
                o = make_float4(packh2(ff6, ff7),
                                packh2(ff8, ps0),
                                packh2(ps1, ps2),
                                0.0f);
            }
            ((float4*)(pack + (size_t)n * 8))[h] = o;
        }
    }
}

// Fused: raw -> exp -> ex[] ; also emits u16 copy of idx0. NO atomics.
__global__ __launch_bounds__(256) void edge_fused_kernel(
    const int* __restrict__ idx,
    const float* __restrict__ packA,
    const float* __restrict__ packB,
    const float* __restrict__ Wattn,
    float* __restrict__ ex,
    unsigned short* __restrict__ i016,
    int E)
{
    int e = blockIdx.x * 256 + threadIdx.x;
    if (e >= E) return;
    int i0 = __builtin_nontemporal_load(idx + e);
    int i1 = __builtin_nontemporal_load(idx + E + e);
    const float4* pa = (const float4*)(packA + (size_t)i0 * 8);
    const float4* pb = (const float4*)(packB + (size_t)i1 * 8);
    float4 a0 = pa[0], a1 = pa[1];
    float4 b0 = pb[0], b1 = pb[1];

    float2 t;
    t = unpackh2(a0.y); float af0 = t.x, af1 = t.y;
    t = unpackh2(a0.z); float af2 = t.x, af3 = t.y;
    t = unpackh2(a0.w); float af4 = t.x, af5 = t.y;
    t = unpackh2(a1.x); float af6 = t.x, af7 = t.y;
    t = unpackh2(a1.y); float af8 = t.x, ap0 = t.y;
    t = unpackh2(a1.z); float ap1 = t.x, ap2 = t.y;
    t = unpackh2(b0.y); float bf0 = t.x, bf1 = t.y;
    t = unpackh2(b0.z); float bf2 = t.x, bf3 = t.y;
    t = unpackh2(b0.w); float bf4 = t.x, bf5 = t.y;
    t = unpackh2(b1.x); float bf6 = t.x, bf7 = t.y;
    t = unpackh2(b1.y); float bf8 = t.x, bp0 = t.y;
    t = unpackh2(b1.z); float bp1 = t.x, bp2 = t.y;

    float d0 = bp0 - ap0, d1 = bp1 - ap1, d2 = bp2 - ap2;
    float pdf0 = d0*af0 + d1*af3 + d2*af6;
    float pdf1 = d0*af1 + d1*af4 + d2*af7;
    float pdf2 = d0*af2 + d1*af5 + d2*af8;
    float pdt0 = -(d0*bf0 + d1*bf3 + d2*bf6);
    float pdt1 = -(d0*bf1 + d1*bf4 + d2*bf7);
    float pdt2 = -(d0*bf2 + d1*bf5 + d2*bf8);

    float r = a0.x + b0.x;
    r += silu_f(pdf0) * Wattn[112] + silu_f(pdf1) * Wattn[113] + silu_f(pdf2) * Wattn[114];
    r += silu_f(pdt0) * Wattn[163] + silu_f(pdt1) * Wattn[164] + silu_f(pdt2) * Wattn[165];

    ex[e] = __expf(r);
    i016[e] = (unsigned short)i0;
}

// Ownership-partitioned segmented sum. Block (r, s): scans edge-slice s,
// LDS-accumulates nodes in range r, writes a non-atomic partial.
__global__ __launch_bounds__(512) void den_scan_kernel(
    const unsigned short* __restrict__ i016,
    const float* __restrict__ ex,
    float* __restrict__ den_part,     // [SPLITS][DP_STRIDE]
    int E, int N)
{
    const int s = blockIdx.x & (SPLITS - 1);   // low bits: XCD-affine slice reuse
    const int r = blockIdx.x / SPLITS;
    const int rn = (N + RANGES - 1) / RANGES;  // 6250 for N=50000
    const int base = r * rn;

    extern __shared__ float lden[];            // rn floats (25KB)
    for (int i = threadIdx.x; i < rn; i += 512) lden[i] = 0.0f;
    __syncthreads();

    const int es = (E + SPLITS - 1) / SPLITS;
    const int e0 = s * es;
    const int e1 = min(e0 + es, E);

    #pragma unroll 4
    for (int e = e0 + threadIdx.x; e < e1; e += 512){
        unsigned d = (unsigned)i016[e] - (unsigned)base;
        if (d < (unsigned)rn){
            atomicAdd(&lden[d], ex[e]);        // LDS atomic: fast HW path
        }
    }
    __syncthreads();

    float* dp = den_part + (size_t)s * DP_STRIDE + base;
    for (int i = threadIdx.x; i < rn && base + i < N; i += 512) dp[i] = lden[i];
}

// collapse the SPLITS partial sums; store reciprocal so edge_out multiplies
__global__ __launch_bounds__(256) void collapse_kernel(
    const float* __restrict__ den_part,
    float* __restrict__ inv_den,
    int N)
{
    int i = blockIdx.x * 256 + threadIdx.x;
    if (i >= N) return;
    float sum = 0.f;
    #pragma unroll
    for (int s = 0; s < SPLITS; s++)
        sum += __builtin_nontemporal_load(den_part + (size_t)s * DP_STRIDE + i);
    inv_den[i] = 1.0f / sum;
}

__global__ __launch_bounds__(256) void edge_out_kernel(
    const unsigned short* __restrict__ i016,
    const float* __restrict__ ex,
    const float* __restrict__ inv_den,
    float* __restrict__ out,
    int E)
{
    int e = blockIdx.x * 256 + threadIdx.x;
    if (e >= E) return;
    int i0 = (int)__builtin_nontemporal_load(i016 + e);
    float v = __builtin_nontemporal_load(ex + e) * inv_den[i0];
    __builtin_nontemporal_store(v, out + e);
}

extern "C" void kernel_launch(void* const* d_in, const int* in_sizes, int n_in,
                              void* d_out, int out_size, void* d_ws, size_t ws_size,
                              hipStream_t stream)
{
    const float* from_s  = (const float*)d_in[0];
    const float* from_v  = (const float*)d_in[1];
    const float* to_s    = (const float*)d_in[2];
    const float* to_v    = (const float*)d_in[3];
    const float* from_fr = (const float*)d_in[4];
    const float* to_fr   = (const float*)d_in[5];
    const float* from_p  = (const float*)d_in[6];
    const float* to_p    = (const float*)d_in[7];
    const float* Wfs     = (const float*)d_in[8];
    const float* Wts     = (const float*)d_in[9];
    const float* Wfv     = (const float*)d_in[10];
    const float* Wtv     = (const float*)d_in[11];
    const float* Wattn   = (const float*)d_in[12];
    const int*   idx     = (const int*)d_in[13];

    int N = in_sizes[0] / NS;
    int E = in_sizes[13] / 2;
    float* out = (float*)d_out;

    char* ws = (char*)d_ws;
    size_t packBytes = (size_t)N * 8 * sizeof(float);
    float*          packA    = (float*)(ws);
    float*          packB    = (float*)(ws + packBytes);
    float*          ex       = (float*)(ws + 2 * packBytes);
    float*          den_part = (float*)(ws + 2 * packBytes + (size_t)E * 4);
    float*          inv_den  = (float*)(ws + 2 * packBytes + (size_t)E * 4
                                         + (size_t)SPLITS * DP_STRIDE * 4);
    unsigned short* i016     = (unsigned short*)(ws + 2 * packBytes + (size_t)E * 4
                                         + (size_t)SPLITS * DP_STRIDE * 4
                                         + (size_t)N * 4 + 256);

    dim3 ngrid(NPGRID, 2);
    node_pack_kernel<<<ngrid, 256, 0, stream>>>(
        from_s, from_v, from_fr, from_p,
        to_s, to_v, to_fr, to_p,
        Wfs, Wts, Wfv, Wtv, Wattn,
        packA, packB, N);

    int nb_e = (E + 255) / 256;
    edge_fused_kernel<<<nb_e, 256, 0, stream>>>(idx, packA, packB, Wattn, ex, i016, E);

    int rn = (N + RANGES - 1) / RANGES;
    size_t lds_bytes = (size_t)rn * sizeof(float);
    den_scan_kernel<<<RANGES * SPLITS, 512, lds_bytes, stream>>>(i016, ex, den_part, E, N);
    collapse_kernel<<<(N + 255) / 256, 256, 0, stream>>>(den_part, inv_den, N);
    edge_out_kernel<<<nb_e, 256, 0, stream>>>(i016, ex, inv_den, out, E);
}

// Round 12
// 115.912 us; speedup vs baseline: 1.2813x; 1.2813x over previous
//
#include <hip/hip_runtime.h>
#include <hip/hip_fp16.h>
#include <math.h>

#define NS 64
#define NV 16
#define NHS 32
#define NHV 16
#define CHUNK 64         // nodes per block in node_pack
#define NA 4             // nodes per 16-lane group (weight-reuse factor)
#define WS_PAD 68        // padded row stride for Ws in LDS
#define WV_PAD 20        // padded row stride for Wv in LDS (16B-aligned rows)
#define LS_PAD 68        // padded per-node stride for staged s
#define LV_PAD 52        // padded per-node stride for staged v

// den_scan geometry (unchanged from R10)
#define RANGES 8
#define SPLITS 32
#define DP_STRIDE 50176

__device__ __forceinline__ float silu_f(float x){ return x * (1.0f / (1.0f + __expf(-x))); }

__device__ __forceinline__ float packh2(float a, float b){
    __half2 h = __floats2half2_rn(a, b);
    return __uint_as_float(*(unsigned*)&h);
}
__device__ __forceinline__ float2 unpackh2(float w){
    __half2 h = *(__half2*)&w;
    return __half22float2(h);
}

// Per-node precompute: pack[n] = 32B = {A fp32, ff[9]+pos[3] as fp16}
// Register-blocked: 16-lane group x 4 nodes; weight b128 reads amortized 4x.
__global__ __launch_bounds__(256) void node_pack_kernel(
    const float* __restrict__ from_s, const float* __restrict__ from_v,
    const float* __restrict__ from_fr, const float* __restrict__ from_p,
    const float* __restrict__ to_s, const float* __restrict__ to_v,
    const float* __restrict__ to_fr, const float* __restrict__ to_p,
    const float* __restrict__ Wfs, const float* __restrict__ Wts,
    const float* __restrict__ Wfv, const float* __restrict__ Wtv,
    const float* __restrict__ Wattn,
    float* __restrict__ packA, float* __restrict__ packB,
    int N)
{
    const int side = blockIdx.y;
    const float* node_s = side ? to_s  : from_s;
    const float* node_v = side ? to_v  : from_v;
    const float* frame  = side ? to_fr : from_fr;
    const float* pos    = side ? to_p  : from_p;
    const float* Ws     = side ? Wts   : Wfs;
    const float* Wv     = side ? Wtv   : Wfv;
    const int    s_off  = side ? 32 : 0;
    const int    v_off  = side ? 115 : 64;
    float*       pack   = side ? packB : packA;

    __shared__ float lws[NHS * WS_PAD];       // 8.7 KB
    __shared__ float lwv[NHV * WV_PAD];       // 1.3 KB
    __shared__ float lwa[NHS + NHV * 3];      // 80
    __shared__ float ls[CHUNK * LS_PAD];      // 17.4 KB
    __shared__ float lv[CHUNK * LV_PAD];      // 13.3 KB
    __shared__ float lf[CHUNK * 9];           // 2.3 KB
    __shared__ float lp[CHUNK * 3];           // 0.8 KB

    const int tid = threadIdx.x;

    // weights -> LDS (padded)
    for (int i = tid; i < NHS * NS; i += 256) lws[(i >> 6) * WS_PAD + (i & 63)] = Ws[i];
    if (tid < NHV * NV) lwv[(tid >> 4) * WV_PAD + (tid & 15)] = Wv[tid];
    if (tid < NHS) lwa[tid] = Wattn[s_off + tid];
    if (tid < NHV * 3) lwa[NHS + tid] = Wattn[v_off + tid];

    const int nbase = blockIdx.x * CHUNK;
    const int cnt = min(CHUNK, N - nbase);

    // stage node data -> LDS (coalesced global reads, padded LDS writes)
    {
        const float4* sp = (const float4*)(node_s + (size_t)nbase * NS);
        for (int i4 = tid; i4 < cnt * 16; i4 += 256){
            int nd = i4 >> 4, k = i4 & 15;
            *(float4*)(ls + nd * LS_PAD + k * 4) = sp[i4];
        }
        const float4* vp = (const float4*)(node_v + (size_t)nbase * (NV * 3));
        for (int i4 = tid; i4 < cnt * 12; i4 += 256){
            int nd = i4 / 12, p = i4 - nd * 12;
            *(float4*)(lv + nd * LV_PAD + p * 4) = vp[i4];
        }
        for (int i = tid; i < cnt * 9; i += 256) lf[i] = frame[(size_t)nbase * 9 + i];
        for (int i = tid; i < cnt * 3; i += 256) lp[i] = pos[(size_t)nbase * 3 + i];
    }
    __syncthreads();

    const int g = tid >> 4;       // group 0..15, handles nodes g*NA .. g*NA+3
    const int l = tid & 15;       // lane = scalar rows l, l+16 ; vector row l

    // ---- scalar GEMV, weights amortized over NA nodes ----
    float d0[NA], d1[NA];
    #pragma unroll
    for (int j = 0; j < NA; j++){ d0[j] = 0.f; d1[j] = 0.f; }
    {
        const float* wr0 = lws + l * WS_PAD;
        const float* wr1 = lws + (l + 16) * WS_PAD;
        #pragma unroll
        for (int k4 = 0; k4 < 16; k4++){
            float4 w0 = *(const float4*)(wr0 + k4 * 4);
            float4 w1 = *(const float4*)(wr1 + k4 * 4);
            #pragma unroll
            for (int j = 0; j < NA; j++){
                float4 sv = *(const float4*)(ls + (g * NA + j) * LS_PAD + k4 * 4);
                d0[j] += sv.x * w0.x + sv.y * w0.y + sv.z * w0.z + sv.w * w0.w;
                d1[j] += sv.x * w1.x + sv.y * w1.y + sv.z * w1.z + sv.w * w1.w;
            }
        }
    }
    const float waS0 = lwa[l], waS1 = lwa[l + 16];
    const float waV0 = lwa[NHS + l * 3 + 0];
    const float waV1 = lwa[NHS + l * 3 + 1];
    const float waV2 = lwa[NHS + l * 3 + 2];

    float4 wv4[4];
    #pragma unroll
    for (int i = 0; i < 4; i++) wv4[i] = *(const float4*)(lwv + l * WV_PAD + i * 4);

    #pragma unroll
    for (int j = 0; j < NA; j++){
        const int nd = g * NA + j;
        if (nd >= cnt) break;                 // group-uniform guard
        const int n = nbase + nd;

        float acc = silu_f(d0[j]) * waS0 + silu_f(d1[j]) * waS1;

        // vector GEMV row l: b128 reads of this node's v
        const float* vb = lv + nd * LV_PAD;
        float a0 = 0.f, a1 = 0.f, a2 = 0.f;
        #pragma unroll
        for (int g4 = 0; g4 < 4; g4++){
            float4 x = *(const float4*)(vb + g4 * 12 + 0);
            float4 y = *(const float4*)(vb + g4 * 12 + 4);
            float4 z = *(const float4*)(vb + g4 * 12 + 8);
            float4 w = wv4[g4];
            a0 += x.x * w.x + x.w * w.y + y.z * w.z + z.y * w.w;
            a1 += x.y * w.x + y.x * w.y + y.w * w.z + z.z * w.w;
            a2 += x.z * w.x + y.y * w.y + z.x * w.z + z.w * w.w;
        }

        const float* fb = lf + nd * 9;
        float ff0 = fb[0], ff1 = fb[1], ff2 = fb[2];
        float ff3 = fb[3], ff4 = fb[4], ff5 = fb[5];
        float ff6 = fb[6], ff7 = fb[7], ff8 = fb[8];
        const float* pb = lp + nd * 3;
        float ps0 = pb[0], ps1 = pb[1], ps2 = pb[2];

        float t0 = a0 * ff0 + a1 * ff3 + a2 * ff6;
        float t1 = a0 * ff1 + a1 * ff4 + a2 * ff7;
        float t2 = a0 * ff2 + a1 * ff5 + a2 * ff8;
        acc += silu_f(t0) * waV0 + silu_f(t1) * waV1 + silu_f(t2) * waV2;

        // reduce over the 16 lanes of the group
        acc += __shfl_xor(acc, 8, 16);
        acc += __shfl_xor(acc, 4, 16);
        acc += __shfl_xor(acc, 2, 16);
        acc += __shfl_xor(acc, 1, 16);

        if (l < 2){
            float4 o;
            if (l == 0){
                o = make_float4(acc,
                                packh2(ff0, ff1),
                                packh2(ff2, ff3),
                                packh2(ff4, ff5));
            } else {
                o = make_float4(packh2(ff6, ff7),
                                packh2(ff8, ps0),
                                packh2(ps1, ps2),
                                0.0f);
            }
            ((float4*)(pack + (size_t)n * 8))[l] = o;
        }
    }
}

// Fused: raw -> exp -> ex[] ; also emits u16 copy of idx0. NO atomics.
__global__ __launch_bounds__(256) void edge_fused_kernel(
    const int* __restrict__ idx,
    const float* __restrict__ packA,
    const float* __restrict__ packB,
    const float* __restrict__ Wattn,
    float* __restrict__ ex,
    unsigned short* __restrict__ i016,
    int E)
{
    int e = blockIdx.x * 256 + threadIdx.x;
    if (e >= E) return;
    int i0 = __builtin_nontemporal_load(idx + e);
    int i1 = __builtin_nontemporal_load(idx + E + e);
    const float4* pa = (const float4*)(packA + (size_t)i0 * 8);
    const float4* pb = (const float4*)(packB + (size_t)i1 * 8);
    float4 a0 = pa[0], a1 = pa[1];
    float4 b0 = pb[0], b1 = pb[1];

    float2 t;
    t = unpackh2(a0.y); float af0 = t.x, af1 = t.y;
    t = unpackh2(a0.z); float af2 = t.x, af3 = t.y;
    t = unpackh2(a0.w); float af4 = t.x, af5 = t.y;
    t = unpackh2(a1.x); float af6 = t.x, af7 = t.y;
    t = unpackh2(a1.y); float af8 = t.x, ap0 = t.y;
    t = unpackh2(a1.z); float ap1 = t.x, ap2 = t.y;
    t = unpackh2(b0.y); float bf0 = t.x, bf1 = t.y;
    t = unpackh2(b0.z); float bf2 = t.x, bf3 = t.y;
    t = unpackh2(b0.w); float bf4 = t.x, bf5 = t.y;
    t = unpackh2(b1.x); float bf6 = t.x, bf7 = t.y;
    t = unpackh2(b1.y); float bf8 = t.x, bp0 = t.y;
    t = unpackh2(b1.z); float bp1 = t.x, bp2 = t.y;

    float d0 = bp0 - ap0, d1 = bp1 - ap1, d2 = bp2 - ap2;
    float pdf0 = d0*af0 + d1*af3 + d2*af6;
    float pdf1 = d0*af1 + d1*af4 + d2*af7;
    float pdf2 = d0*af2 + d1*af5 + d2*af8;
    float pdt0 = -(d0*bf0 + d1*bf3 + d2*bf6);
    float pdt1 = -(d0*bf1 + d1*bf4 + d2*bf7);
    float pdt2 = -(d0*bf2 + d1*bf5 + d2*bf8);

    float r = a0.x + b0.x;
    r += silu_f(pdf0) * Wattn[112] + silu_f(pdf1) * Wattn[113] + silu_f(pdf2) * Wattn[114];
    r += silu_f(pdt0) * Wattn[163] + silu_f(pdt1) * Wattn[164] + silu_f(pdt2) * Wattn[165];

    ex[e] = __expf(r);
    i016[e] = (unsigned short)i0;
}

// Ownership-partitioned segmented sum. Block (r, s): scans edge-slice s,
// LDS-accumulates nodes in range r, writes a non-atomic partial.
__global__ __launch_bounds__(512) void den_scan_kernel(
    const unsigned short* __restrict__ i016,
    const float* __restrict__ ex,
    float* __restrict__ den_part,     // [SPLITS][DP_STRIDE]
    int E, int N)
{
    const int s = blockIdx.x & (SPLITS - 1);   // low bits: XCD-affine slice reuse
    const int r = blockIdx.x / SPLITS;
    const int rn = (N + RANGES - 1) / RANGES;  // 6250 for N=50000
    const int base = r * rn;

    extern __shared__ float lden[];            // rn floats (25KB)
    for (int i = threadIdx.x; i < rn; i += 512) lden[i] = 0.0f;
    __syncthreads();

    const int es = (E + SPLITS - 1) / SPLITS;
    const int e0 = s * es;
    const int e1 = min(e0 + es, E);

    #pragma unroll 4
    for (int e = e0 + threadIdx.x; e < e1; e += 512){
        unsigned d = (unsigned)i016[e] - (unsigned)base;
        if (d < (unsigned)rn){
            atomicAdd(&lden[d], ex[e]);        // LDS atomic: fast HW path
        }
    }
    __syncthreads();

    float* dp = den_part + (size_t)s * DP_STRIDE + base;
    for (int i = threadIdx.x; i < rn && base + i < N; i += 512) dp[i] = lden[i];
}

// collapse the SPLITS partial sums; store reciprocal so edge_out multiplies
__global__ __launch_bounds__(256) void collapse_kernel(
    const float* __restrict__ den_part,
    float* __restrict__ inv_den,
    int N)
{
    int i = blockIdx.x * 256 + threadIdx.x;
    if (i >= N) return;
    float sum = 0.f;
    #pragma unroll
    for (int s = 0; s < SPLITS; s++)
        sum += __builtin_nontemporal_load(den_part + (size_t)s * DP_STRIDE + i);
    inv_den[i] = 1.0f / sum;
}

__global__ __launch_bounds__(256) void edge_out_kernel(
    const unsigned short* __restrict__ i016,
    const float* __restrict__ ex,
    const float* __restrict__ inv_den,
    float* __restrict__ out,
    int E)
{
    int e = blockIdx.x * 256 + threadIdx.x;
    if (e >= E) return;
    int i0 = (int)__builtin_nontemporal_load(i016 + e);
    float v = __builtin_nontemporal_load(ex + e) * inv_den[i0];
    __builtin_nontemporal_store(v, out + e);
}

extern "C" void kernel_launch(void* const* d_in, const int* in_sizes, int n_in,
                              void* d_out, int out_size, void* d_ws, size_t ws_size,
                              hipStream_t stream)
{
    const float* from_s  = (const float*)d_in[0];
    const float* from_v  = (const float*)d_in[1];
    const float* to_s    = (const float*)d_in[2];
    const float* to_v    = (const float*)d_in[3];
    const float* from_fr = (const float*)d_in[4];
    const float* to_fr   = (const float*)d_in[5];
    const float* from_p  = (const float*)d_in[6];
    const float* to_p    = (const float*)d_in[7];
    const float* Wfs     = (const float*)d_in[8];
    const float* Wts     = (const float*)d_in[9];
    const float* Wfv     = (const float*)d_in[10];
    const float* Wtv     = (const float*)d_in[11];
    const float* Wattn   = (const float*)d_in[12];
    const int*   idx     = (const int*)d_in[13];

    int N = in_sizes[0] / NS;
    int E = in_sizes[13] / 2;
    float* out = (float*)d_out;

    char* ws = (char*)d_ws;
    size_t packBytes = (size_t)N * 8 * sizeof(float);
    float*          packA    = (float*)(ws);
    float*          packB    = (float*)(ws + packBytes);
    float*          ex       = (float*)(ws + 2 * packBytes);
    float*          den_part = (float*)(ws + 2 * packBytes + (size_t)E * 4);
    float*          inv_den  = (float*)(ws + 2 * packBytes + (size_t)E * 4
                                         + (size_t)SPLITS * DP_STRIDE * 4);
    unsigned short* i016     = (unsigned short*)(ws + 2 * packBytes + (size_t)E * 4
                                         + (size_t)SPLITS * DP_STRIDE * 4
                                         + (size_t)N * 4 + 256);

    dim3 ngrid((N + CHUNK - 1) / CHUNK, 2);
    node_pack_kernel<<<ngrid, 256, 0, stream>>>(
        from_s, from_v, from_fr, from_p,
        to_s, to_v, to_fr, to_p,
        Wfs, Wts, Wfv, Wtv, Wattn,
        packA, packB, N);

    int nb_e = (E + 255) / 256;
    edge_fused_kernel<<<nb_e, 256, 0, stream>>>(idx, packA, packB, Wattn, ex, i016, E);

    int rn = (N + RANGES - 1) / RANGES;
    size_t lds_bytes = (size_t)rn * sizeof(float);
    den_scan_kernel<<<RANGES * SPLITS, 512, lds_bytes, stream>>>(i016, ex, den_part, E, N);
    collapse_kernel<<<(N + 255) / 256, 256, 0, stream>>>(den_part, inv_den, N);
    edge_out_kernel<<<nb_e, 256, 0, stream>>>(i016, ex, inv_den, out, E);
}